// Round 6
// baseline (94.830 us; speedup 1.0000x reference)
//
#include <hip/hip_runtime.h>
#include <math.h>

#define BT     1024
#define GRID   256
#define NITEMS 4
#define NROW   100
#define DDIM   768
#define EPS_LN 1e-5f
#define EPSF   1e-8f

// LDS layout (bytes), total 160948 <= 163840:
//   u    : [100][384] uint (bf16 pairs; word j <-> cols 2j,2j+1) @ 0   (153600)
//   S    : [768] f32  @ 153600  (3072)
//   gbL  : [768] uint @ 156672  (3072)  [0..383]=gamma bf16 pairs, [384..767]=beta
//   nrm  : [100] f32  @ 159744  (400)
//   dens : [100] f32  @ 160144  (400)
//   w2   : [100] f32  @ 160544  (400)
//   Wsh  : [1]  f32   @ 160944  (4)
#define LDS_BYTES 160948

// Barrier WITHOUT vmcnt drain: LDS producer/consumer safety via lgkmcnt(0),
// but global prefetch loads stay in flight across it (unlike __syncthreads,
// which drains vmcnt(0) and would serialize prefetch with the tail).
#define BARRIER() asm volatile("s_waitcnt lgkmcnt(0)\n\ts_barrier" ::: "memory")

__device__ __forceinline__ float bflo(unsigned int p) {
    union { unsigned int u; float f; } c; c.u = p << 16; return c.f;
}
__device__ __forceinline__ float bfhi(unsigned int p) {
    union { unsigned int u; float f; } c; c.u = p & 0xFFFF0000u; return c.f;
}
__device__ __forceinline__ unsigned int cvtpk(float lo, float hi) {
    unsigned int r;
    asm("v_cvt_pk_bf16_f32 %0, %1, %2" : "=v"(r) : "v"(lo), "v"(hi));
    return r;   // lo -> bits [15:0], hi -> bits [31:16], RNE
}
__device__ __forceinline__ float wave_sum(float v) {
#pragma unroll
    for (int m = 32; m >= 1; m >>= 1) v += __shfl_xor(v, m, 64);
    return v;
}
__device__ __forceinline__ float half_sum(float v) {
#pragma unroll
    for (int m = 16; m >= 1; m >>= 1) v += __shfl_xor(v, m, 64);
    return v;
}

extern "C" __global__ void __launch_bounds__(BT, 4)
ccs_kernel(const float* __restrict__ x,
           const float* __restrict__ cc,
           const float* __restrict__ alpha,
           const float* __restrict__ gamma,
           const float* __restrict__ beta,
           const float* __restrict__ thw,
           const float* __restrict__ thb,
           float* __restrict__ out)
{
    extern __shared__ char lds[];
    unsigned int* u   = (unsigned int*)lds;            // [100][384]
    float*        S   = (float*)(lds + 153600);
    unsigned int* gbL = (unsigned int*)(lds + 156672); // gamma/beta bf16 pairs
    float*        nrm = (float*)(lds + 159744);
    float*        dens= (float*)(lds + 160144);
    float*        w2  = (float*)(lds + 160544);
    float*        Wsh = (float*)(lds + 160944);

    const int tid = threadIdx.x;
    const int w   = tid >> 6;
    const int l   = tid & 63;
    const int li  = l & 31;                 // lane within half-wave
    const int hw  = (w << 1) | (l >> 5);    // half-wave id 0..31
    const int b   = blockIdx.x;

    // ---- hoisted tiny loads (live in registers for the whole kernel) ----
    float thwa = 0.f, thwb = 0.f, alphav = 0.f, thbv = 0.f;
    if (w == 0) {
        thwa = thw[l];
        if (l < NROW - 64) thwb = thw[64 + l];
        alphav = alpha[0];
        thbv   = thb[0];
    }

    const int base = 4 * li;
    const int pcnt = (hw < 4) ? 4 : 3;      // pass-1 rows n = hw + 32r
    const int cnt  = (w  < 4) ? 7 : 6;      // pass-2a rows n = w + 16r

    // ---- item 0: issue first row's loads immediately ----
    float xf[24];
    {
        const float* xr = x + (size_t)b * (NROW * DDIM) + hw * DDIM + base;
#pragma unroll
        for (int k = 0; k < 6; ++k)
            *(float4*)&xf[4 * k] = *(const float4*)(xr + 128 * k);
    }

    // ---- stage gamma/beta once as bf16 pairs (overlaps with loads in flight) ----
    if (tid < 384) {
        const float2 g2 = *(const float2*)(gamma + 2 * tid);
        const float2 b2 = *(const float2*)(beta  + 2 * tid);
        gbL[tid]       = cvtpk(g2.x, g2.y);
        gbL[384 + tid] = cvtpk(b2.x, b2.y);
    }
    BARRIER();

    for (int it = 0; it < NITEMS; ++it) {
        const int bi = b + GRID * it;
        const float* xb = x + (size_t)bi * (NROW * DDIM);

        // ---------- Pass 1: half-wave per row ----------
#pragma unroll
        for (int r = 0; r < 4; ++r) {
            if (r >= pcnt) break;
            const int row = hw + 32 * r;

            float p0 = 0.f, p1 = 0.f;
#pragma unroll
            for (int m = 0; m < 24; ++m) { p0 += xf[m]; p1 += xf[m] * xf[m]; }

            float xn1[24];
            if (r + 1 < pcnt) {             // prefetch next row before the chain
                const float* xr = xb + (row + 32) * DDIM + base;
#pragma unroll
                for (int k = 0; k < 6; ++k)
                    *(float4*)&xn1[4 * k] = *(const float4*)(xr + 128 * k);
            }

#pragma unroll
            for (int m = 16; m >= 1; m >>= 1) {
                p0 += __shfl_xor(p0, m, 64);
                p1 += __shfl_xor(p1, m, 64);
            }
            const float mu   = p0 * (1.0f / DDIM);
            const float var  = p1 * (1.0f / DDIM) - mu * mu;
            const float A    = rsqrtf(var + EPS_LN);
            const float nmuA = -mu * A;

            float q = 0.f;
#pragma unroll
            for (int k = 0; k < 6; ++k) {
                const uint2 gw = *(const uint2*)&gbL[64 * k + 2 * li];
                const uint2 bw = *(const uint2*)&gbL[384 + 64 * k + 2 * li];
                const float g0 = bflo(gw.x), g1 = bfhi(gw.x), g2 = bflo(gw.y), g3 = bfhi(gw.y);
                const float b0 = bflo(bw.x), b1 = bfhi(bw.x), b2 = bflo(bw.y), b3 = bfhi(bw.y);
                float t, v;
                t = fmaf(xf[4*k+0], A, nmuA); v = fmaf(t, g0, b0); xf[4*k+0] = v; q += v * v;
                t = fmaf(xf[4*k+1], A, nmuA); v = fmaf(t, g1, b1); xf[4*k+1] = v; q += v * v;
                t = fmaf(xf[4*k+2], A, nmuA); v = fmaf(t, g2, b2); xf[4*k+2] = v; q += v * v;
                t = fmaf(xf[4*k+3], A, nmuA); v = fmaf(t, g3, b3); xf[4*k+3] = v; q += v * v;
            }
            q = half_sum(q);
            const float qc  = fmaxf(q, 1e-30f);
            const float inv = rsqrtf(qc);
            const float nr  = qc * inv;     // sqrt(q)

            unsigned int* ur = u + row * 384 + 2 * li;
#pragma unroll
            for (int k = 0; k < 6; ++k) {
                uint2 pk;
                pk.x = cvtpk(xf[4 * k + 0] * inv, xf[4 * k + 1] * inv);
                pk.y = cvtpk(xf[4 * k + 2] * inv, xf[4 * k + 3] * inv);
                *(uint2*)&ur[64 * k] = pk;
            }
            if (li == 0) nrm[row] = nr;

            if (r + 1 < pcnt) {
#pragma unroll
                for (int m = 0; m < 24; ++m) xf[m] = xn1[m];
            }
        }

        // ---- cross-item prefetch: next item's first row, stays in flight
        //      across all tail barriers (no vmcnt drain) ----
        if (it + 1 < NITEMS) {
            const float* xr = x + (size_t)(bi + GRID) * (NROW * DDIM) + hw * DDIM + base;
#pragma unroll
            for (int k = 0; k < 6; ++k)
                *(float4*)&xf[4 * k] = *(const float4*)(xr + 128 * k);
        }
        BARRIER();

        // ---------- Pass S: S[d] = sum_n u[n][d] ----------
        if (tid < 384) {
            float ax = 0.f, ay = 0.f;
            const unsigned int* up = u + tid;
#pragma unroll 4
            for (int n = 0; n < NROW; ++n) {
                const unsigned int pw = up[n * 384];
                ax += bflo(pw); ay += bfhi(pw);
            }
            *(float2*)&S[2 * tid] = make_float2(ax, ay);
        }
        BARRIER();

        // ---------- Pass 2a: density[n] = u_n . S ----------
        float Sv[12];
#pragma unroll
        for (int k = 0; k < 3; ++k)
            *(float4*)&Sv[4 * k] = *(const float4*)&S[k * 256 + 4 * l];

        float dot[7];
#pragma unroll
        for (int r = 0; r < 7; ++r) dot[r] = 0.f;
#pragma unroll
        for (int r = 0; r < 7; ++r) {
            if (r < cnt) {
                const unsigned int* ur = u + (w + 16 * r) * 384;
                float d = 0.f;
#pragma unroll
                for (int k = 0; k < 3; ++k) {
                    const uint2 p = *(const uint2*)&ur[k * 128 + 2 * l];
                    d += bflo(p.x) * Sv[4*k+0] + bfhi(p.x) * Sv[4*k+1]
                       + bflo(p.y) * Sv[4*k+2] + bfhi(p.y) * Sv[4*k+3];
                }
                dot[r] = d;
            }
        }
#pragma unroll
        for (int msk = 32; msk >= 1; msk >>= 1) {
#pragma unroll
            for (int r = 0; r < 7; ++r) dot[r] += __shfl_xor(dot[r], msk, 64);
        }
        if (l == 0) {
#pragma unroll
            for (int r = 0; r < 7; ++r)
                if (r < cnt) dens[w + 16 * r] = dot[r];
        }
        BARRIER();

        // cc load issued here; in flight during pass 2b
        float2 ccv = make_float2(0.f, 0.f);
        if (tid < 384) ccv = *(const float2*)(cc + (size_t)bi * DDIM + 2 * tid);

        // ---------- Pass 2b: min-max normalize, threshold, gate (wave 0) ----------
        if (w == 0) {
            const float va = dens[l];
            const bool  hb = (l < NROW - 64);
            const float vb = hb ? dens[64 + l] : 0.f;

            float mxv = hb ? fmaxf(va, vb) : va;
            float mnv = hb ? fminf(va, vb) : va;
#pragma unroll
            for (int m = 32; m >= 1; m >>= 1) {
                mxv = fmaxf(mxv, __shfl_xor(mxv, m, 64));
                mnv = fminf(mnv, __shfl_xor(mnv, m, 64));
            }
            const float rng = 1.0f / (mxv - mnv + EPSF);
            const float ra  = (va - mnv) * rng;
            const float rb  = (vb - mnv) * rng;

            float td = ra * thwa + (hb ? rb * thwb : 0.f);
            td = wave_sum(td);
            const float z  = td + thbv;
            const float th = alphav / (1.0f + expf(-z));

            const float ga  = fmaxf(ra - th, 0.f);
            const float gb_ = hb ? fmaxf(rb - th, 0.f) : 0.f;
            const float sg  = wave_sum(ga + gb_);
            const float wf  = 1.0f / (sg + EPSF);

            w2[l] = ga * wf * nrm[l];
            if (hb) w2[64 + l] = gb_ * wf * nrm[64 + l];
            if (l == 0) Wsh[0] = sg * wf;
        }
        BARRIER();

        // ---------- Pass 3 + output ----------
        if (tid < 384) {
            float ax = 0.f, ay = 0.f;
            const unsigned int* up = u + tid;
#pragma unroll 4
            for (int n = 0; n < NROW; ++n) {
                const float wv = w2[n];
                const unsigned int pw = up[n * 384];
                ax += wv * bflo(pw); ay += wv * bfhi(pw);
            }
            const float W = Wsh[0];
            float2 o;
            o.x = ccv.x + (ax - ccv.x * W) * (1.0f / NROW);
            o.y = ccv.y + (ay - ccv.y * W) * (1.0f / NROW);
            *(float2*)(out + (size_t)bi * DDIM + 2 * tid) = o;
        }
        BARRIER();   // u reads complete before next item's pass-1 rewrites u
    }
}

extern "C" void kernel_launch(void* const* d_in, const int* in_sizes, int n_in,
                              void* d_out, int out_size, void* d_ws, size_t ws_size,
                              hipStream_t stream) {
    const float* x     = (const float*)d_in[0];
    const float* cc    = (const float*)d_in[1];
    const float* alpha = (const float*)d_in[2];
    const float* gamma = (const float*)d_in[3];
    const float* beta  = (const float*)d_in[4];
    const float* thw   = (const float*)d_in[5];
    const float* thb   = (const float*)d_in[6];
    float* out = (float*)d_out;

    ccs_kernel<<<GRID, BT, LDS_BYTES, stream>>>(x, cc, alpha, gamma, beta, thw, thb, out);
}

// Round 7
// 81.185 us; speedup vs baseline: 1.1681x; 1.1681x over previous
//
#include <hip/hip_runtime.h>
#include <math.h>

#define BT     1024
#define NROW   100
#define DDIM   768
#define EPS_LN 1e-5f
#define EPSF   1e-8f

// LDS layout (bytes), total 157876:
//   u    : [100][384] uint (bf16 pairs; word j <-> cols 2j,2j+1) @ 0 (153600)
//   S    : [768] f32 @ 153600
//   nrm  : [100] f32 @ 156672
//   dens : [100] f32 @ 157072
//   w2   : [100] f32 @ 157472
//   Wsh  : [1]  f32 @ 157872
#define LDS_BYTES 157876

__device__ __forceinline__ float bflo(unsigned int p) {
    union { unsigned int u; float f; } c; c.u = p << 16; return c.f;
}
__device__ __forceinline__ float bfhi(unsigned int p) {
    union { unsigned int u; float f; } c; c.u = p & 0xFFFF0000u; return c.f;
}
__device__ __forceinline__ unsigned int cvtpk(float lo, float hi) {
    unsigned int r;
    asm("v_cvt_pk_bf16_f32 %0, %1, %2" : "=v"(r) : "v"(lo), "v"(hi));
    return r;
}
__device__ __forceinline__ float wave_sum(float v) {
#pragma unroll
    for (int m = 32; m >= 1; m >>= 1) v += __shfl_xor(v, m, 64);
    return v;
}

// DPP add step: v += dpp_select(v); bound_ctrl=true -> OOB lanes read 0
#define DPPADD(v, ctrl) \
    v += __int_as_float(__builtin_amdgcn_update_dpp(0, __float_as_int(v), ctrl, 0xf, 0xf, true))

// Sum within each 32-lane half via DPP (row_shr 1,2,4,8 + bcast15);
// half-sums land in lanes 31 and 63.
__device__ __forceinline__ float dpp_half_sum(float v) {
    DPPADD(v, 0x111);   // row_shr:1
    DPPADD(v, 0x112);   // row_shr:2
    DPPADD(v, 0x114);   // row_shr:4
    DPPADD(v, 0x118);   // row_shr:8  -> lane15 of each 16-row = row sum
    DPPADD(v, 0x142);   // bcast15    -> lane31/lane63 = 32-half sums
    return v;
}
// + broadcast the half-sum to all lanes of the half (lane' = 31 within each 32-group)
__device__ __forceinline__ float dpp_half_sum_bcast(float v) {
    v = dpp_half_sum(v);
    return __int_as_float(__builtin_amdgcn_ds_swizzle(__float_as_int(v), 0x03E0));
}

extern "C" __global__ void __launch_bounds__(BT, 4)
ccs_kernel(const float* __restrict__ x,
           const float* __restrict__ cc,
           const float* __restrict__ alpha,
           const float* __restrict__ gamma,
           const float* __restrict__ beta,
           const float* __restrict__ thw,
           const float* __restrict__ thb,
           float* __restrict__ out)
{
    extern __shared__ char lds[];
    unsigned int* u   = (unsigned int*)lds;        // [100][384]
    float* S    = (float*)(lds + 153600);
    float* nrm  = (float*)(lds + 156672);
    float* dens = (float*)(lds + 157072);
    float* w2   = (float*)(lds + 157472);
    float* Wsh  = (float*)(lds + 157872);

    const int tid = threadIdx.x;
    const int w   = tid >> 6;
    const int l   = tid & 63;
    const int li  = l & 31;                  // lane within 32-half
    const int hw  = (w << 1) | (l >> 5);     // half-wave id 0..31
    const int b   = blockIdx.x;
    const float* xb = x + (size_t)b * (NROW * DDIM);

    const int base = 4 * li;
    const int pcnt = (hw < 4) ? 4 : 3;       // rows n = hw + 32r (wave-uniform)

    // ---- first row's loads issued immediately (critical path) ----
    float xf[24];
    {
        const float* xr = xb + hw * DDIM + base;
#pragma unroll
        for (int k = 0; k < 6; ++k)
            *(float4*)&xf[4 * k] = *(const float4*)(xr + 128 * k);
    }

    // ---- hoisted tiny loads ----
    float thwa = 0.f, thwb = 0.f, alphav = 0.f, thbv = 0.f;
    if (w == 0) {
        thwa = thw[l];
        if (l < NROW - 64) thwb = thw[64 + l];
        alphav = alpha[0];
        thbv   = thb[0];
    }
    float2 ccv = make_float2(0.f, 0.f);
    if (tid < 384) ccv = *(const float2*)(cc + (size_t)b * DDIM + 2 * tid);

    // ---- gamma/beta for this lane's 24 cols, packed bf16 in 12 registers ----
    uint2 gpk[3], bpk[3];
#pragma unroll
    for (int k = 0; k < 3; ++k) {
        const float4 g4 = *(const float4*)(gamma + 256 * k + base);       // cols 4li+256k.. wait
        const float4 g5 = *(const float4*)(gamma + 256 * k + 128 + base);
        const float4 b4 = *(const float4*)(beta  + 256 * k + base);
        const float4 b5 = *(const float4*)(beta  + 256 * k + 128 + base);
        // chunk 2k   -> cols 128*(2k)   + 4li : g4/b4
        // chunk 2k+1 -> cols 128*(2k+1) + 4li : g5/b5
        gpk[k].x = cvtpk(g4.x, g4.y); gpk[k].y = cvtpk(g4.z, g4.w);
        bpk[k].x = cvtpk(b4.x, b4.y); bpk[k].y = cvtpk(b4.z, b4.w);
        // stash odd chunks in xn1-free temps via immediate use below (keep simple: re-pack per row is
        // avoided by storing all 6 chunks; use two arrays of 3 uint2 each covering chunks 0,2,4 / 1,3,5)
        (void)g5; (void)b5;
    }
    // full 6-chunk packed storage (chunks k=0..5), overwrite cleanly:
    uint2 gp6[6], bp6[6];
#pragma unroll
    for (int k = 0; k < 6; ++k) {
        const float4 g4 = *(const float4*)(gamma + 128 * k + base);
        const float4 b4 = *(const float4*)(beta  + 128 * k + base);
        gp6[k].x = cvtpk(g4.x, g4.y); gp6[k].y = cvtpk(g4.z, g4.w);
        bp6[k].x = cvtpk(b4.x, b4.y); bp6[k].y = cvtpk(b4.z, b4.w);
    }

    // ---------- Pass 1: half-wave per row, DPP reductions ----------
#pragma unroll
    for (int r = 0; r < 4; ++r) {
        if (r >= pcnt) break;
        const int row = hw + 32 * r;

        float p0 = 0.f, p1 = 0.f;
#pragma unroll
        for (int m = 0; m < 24; ++m) { p0 += xf[m]; p1 = fmaf(xf[m], xf[m], p1); }

        float xn1[24];
        if (r + 1 < pcnt) {                 // prefetch next row before the chain
            const float* xr = xb + (row + 32) * DDIM + base;
#pragma unroll
            for (int k = 0; k < 6; ++k)
                *(float4*)&xn1[4 * k] = *(const float4*)(xr + 128 * k);
        }

        p0 = dpp_half_sum_bcast(p0);
        p1 = dpp_half_sum_bcast(p1);
        const float mu   = p0 * (1.0f / DDIM);
        const float var  = p1 * (1.0f / DDIM) - mu * mu;
        const float A    = rsqrtf(var + EPS_LN);
        const float nmuA = -mu * A;

        float q = 0.f;
#pragma unroll
        for (int k = 0; k < 6; ++k) {
            const float g0 = bflo(gp6[k].x), g1 = bfhi(gp6[k].x);
            const float g2 = bflo(gp6[k].y), g3 = bfhi(gp6[k].y);
            const float b0 = bflo(bp6[k].x), b1 = bfhi(bp6[k].x);
            const float b2 = bflo(bp6[k].y), b3 = bfhi(bp6[k].y);
            float t, v;
            t = fmaf(xf[4*k+0], A, nmuA); v = fmaf(t, g0, b0); xf[4*k+0] = v; q = fmaf(v, v, q);
            t = fmaf(xf[4*k+1], A, nmuA); v = fmaf(t, g1, b1); xf[4*k+1] = v; q = fmaf(v, v, q);
            t = fmaf(xf[4*k+2], A, nmuA); v = fmaf(t, g2, b2); xf[4*k+2] = v; q = fmaf(v, v, q);
            t = fmaf(xf[4*k+3], A, nmuA); v = fmaf(t, g3, b3); xf[4*k+3] = v; q = fmaf(v, v, q);
        }
        q = dpp_half_sum_bcast(q);
        const float qc  = fmaxf(q, 1e-30f);
        const float inv = rsqrtf(qc);
        const float nr  = qc * inv;        // sqrt(q)

        unsigned int* ur = u + row * 384 + 2 * li;
#pragma unroll
        for (int k = 0; k < 6; ++k) {
            uint2 pk;
            pk.x = cvtpk(xf[4 * k + 0] * inv, xf[4 * k + 1] * inv);
            pk.y = cvtpk(xf[4 * k + 2] * inv, xf[4 * k + 3] * inv);
            *(uint2*)&ur[64 * k] = pk;
        }
        if (li == 0) nrm[row] = nr;

        if (r + 1 < pcnt) {
#pragma unroll
            for (int m = 0; m < 24; ++m) xf[m] = xn1[m];
        }
    }
    __syncthreads();

    // ---------- Pass S: S[d] = sum_n u[n][d] (384 threads, word t = cols 2t,2t+1) ----------
    if (tid < 384) {
        float ax = 0.f, ay = 0.f;
        const unsigned int* up = u + tid;
#pragma unroll 4
        for (int n = 0; n < NROW; ++n) {
            const unsigned int pw = up[n * 384];
            ax += bflo(pw); ay += bfhi(pw);
        }
        *(float2*)&S[2 * tid] = make_float2(ax, ay);
    }
    __syncthreads();

    // ---------- Pass 2a: density[n] = u_n . S  (half-wave rows, b128 reads, DPP tail) ----------
    {
        float Sv[24];   // this lane's cols: 256k + 8li + j, j<8
#pragma unroll
        for (int k = 0; k < 3; ++k) {
            *(float4*)&Sv[8 * k]     = *(const float4*)&S[256 * k + 8 * li];
            *(float4*)&Sv[8 * k + 4] = *(const float4*)&S[256 * k + 8 * li + 4];
        }
#pragma unroll
        for (int r = 0; r < 4; ++r) {
            if (r >= pcnt) break;
            const int row = hw + 32 * r;
            const unsigned int* ur = u + row * 384 + 4 * li;
            float d = 0.f;
#pragma unroll
            for (int k = 0; k < 3; ++k) {
                const uint4 pw = *(const uint4*)&ur[128 * k];
                d = fmaf(bflo(pw.x), Sv[8*k+0], d); d = fmaf(bfhi(pw.x), Sv[8*k+1], d);
                d = fmaf(bflo(pw.y), Sv[8*k+2], d); d = fmaf(bfhi(pw.y), Sv[8*k+3], d);
                d = fmaf(bflo(pw.z), Sv[8*k+4], d); d = fmaf(bfhi(pw.z), Sv[8*k+5], d);
                d = fmaf(bflo(pw.w), Sv[8*k+6], d); d = fmaf(bfhi(pw.w), Sv[8*k+7], d);
            }
            d = dpp_half_sum(d);           // lanes 31/63 hold the row sums
            if (li == 31) dens[row] = d;
        }
    }
    __syncthreads();

    // ---------- Pass 2b: min-max normalize, sigmoid threshold, gate (wave 0) ----------
    if (w == 0) {
        const float va = dens[l];
        const bool  hb = (l < NROW - 64);
        const float vb = hb ? dens[64 + l] : 0.f;

        float mxv = hb ? fmaxf(va, vb) : va;
        float mnv = hb ? fminf(va, vb) : va;
#pragma unroll
        for (int m = 32; m >= 1; m >>= 1) {
            mxv = fmaxf(mxv, __shfl_xor(mxv, m, 64));
            mnv = fminf(mnv, __shfl_xor(mnv, m, 64));
        }
        const float rng = 1.0f / (mxv - mnv + EPSF);
        const float ra  = (va - mnv) * rng;
        const float rb  = (vb - mnv) * rng;

        float td = ra * thwa + (hb ? rb * thwb : 0.f);
        td = wave_sum(td);
        const float z  = td + thbv;
        const float th = alphav / (1.0f + expf(-z));

        const float ga  = fmaxf(ra - th, 0.f);
        const float gb_ = hb ? fmaxf(rb - th, 0.f) : 0.f;
        const float sg  = wave_sum(ga + gb_);
        const float wf  = 1.0f / (sg + EPSF);

        w2[l] = ga * wf * nrm[l];
        if (hb) w2[64 + l] = gb_ * wf * nrm[64 + l];
        if (l == 0) Wsh[0] = sg * wf;
    }
    __syncthreads();

    // ---------- Pass 3 + output ----------
    if (tid < 384) {
        float ax = 0.f, ay = 0.f;
        const unsigned int* up = u + tid;
#pragma unroll 4
        for (int n = 0; n < NROW; ++n) {
            const float wv = w2[n];
            const unsigned int pw = up[n * 384];
            ax = fmaf(wv, bflo(pw), ax); ay = fmaf(wv, bfhi(pw), ay);
        }
        const float W = Wsh[0];
        float2 o;
        o.x = ccv.x + (ax - ccv.x * W) * (1.0f / NROW);
        o.y = ccv.y + (ay - ccv.y * W) * (1.0f / NROW);
        *(float2*)(out + (size_t)b * DDIM + 2 * tid) = o;
    }
}

extern "C" void kernel_launch(void* const* d_in, const int* in_sizes, int n_in,
                              void* d_out, int out_size, void* d_ws, size_t ws_size,
                              hipStream_t stream) {
    const float* x     = (const float*)d_in[0];
    const float* cc    = (const float*)d_in[1];
    const float* alpha = (const float*)d_in[2];
    const float* gamma = (const float*)d_in[3];
    const float* beta  = (const float*)d_in[4];
    const float* thw   = (const float*)d_in[5];
    const float* thb   = (const float*)d_in[6];
    float* out = (float*)d_out;

    ccs_kernel<<<1024, BT, LDS_BYTES, stream>>>(x, cc, alpha, gamma, beta, thw, thb, out);
}